// Round 7
// baseline (254.170 us; speedup 1.0000x reference)
//
#include <hip/hip_runtime.h>
#include <hip/hip_bf16.h>

#define BB 4
#define TT 2048
#define CC 1024
#define HH 16
#define DD 64
#define BT (BB*TT)   // 8192
#define C3 (3*CC)    // 3072
#define LDST 72      // attn P-buffer row stride in bf16 elems (144 B)
#define QSCALE 0.18033688011112042f   // 0.125 * log2(e)

typedef __attribute__((ext_vector_type(8))) short short8;
typedef __attribute__((ext_vector_type(4))) float f32x4;

__device__ __forceinline__ short f2bs(float f) {
  __hip_bfloat16 h = __float2bfloat16(f);
  return *reinterpret_cast<short*>(&h);
}

__device__ __forceinline__ void gl_lds16(const short* g, short* l) {
  __builtin_amdgcn_global_load_lds(
      (const __attribute__((address_space(1))) void*)(g),
      (__attribute__((address_space(3))) void*)(l), 16, 0, 0);
}

// ---------------------------------------------------------------------------
// P: single prep launch (verified R8, unchanged).
// ---------------------------------------------------------------------------
__global__ __launch_bounds__(256)
void prep(const float* __restrict__ Wa, short* __restrict__ Wat,
          const float* __restrict__ Wp, short* __restrict__ Wpt,
          const float* __restrict__ x, short* __restrict__ Xb)
{
  __shared__ float Lt[64][65];
  const int bx = blockIdx.x;
  if (bx >= 64) {
    size_t chunk = (size_t)(bx - 64) * 16 + blockIdx.y;
    size_t i = (chunk * 256 + threadIdx.x) * 8;
    float4 a = *reinterpret_cast<const float4*>(x + i);
    float4 b = *reinterpret_cast<const float4*>(x + i + 4);
    short8 o;
    o[0] = f2bs(a.x); o[1] = f2bs(a.y); o[2] = f2bs(a.z); o[3] = f2bs(a.w);
    o[4] = f2bs(b.x); o[5] = f2bs(b.y); o[6] = f2bs(b.z); o[7] = f2bs(b.w);
    *reinterpret_cast<short8*>(Xb + i) = o;
    return;
  }
  const bool isA = (bx < 48);
  const float* in  = isA ? Wa  : Wp;
  short*       out = isA ? Wat : Wpt;
  const int N  = isA ? C3 : CC;
  const int n0 = (isA ? bx : bx - 48) * 64;
  const int k0 = blockIdx.y * 64;
  const int cx = threadIdx.x & 15, rr = threadIdx.x >> 4;
#pragma unroll
  for (int p = 0; p < 4; ++p) {
    int kr = p * 16 + rr;
    float4 u = *reinterpret_cast<const float4*>(in + (size_t)(k0 + kr) * N + n0 + cx * 4);
    Lt[kr][cx * 4 + 0] = u.x;
    Lt[kr][cx * 4 + 1] = u.y;
    Lt[kr][cx * 4 + 2] = u.z;
    Lt[kr][cx * 4 + 3] = u.w;
  }
  __syncthreads();
#pragma unroll
  for (int p = 0; p < 4; ++p) {
    int nr = p * 16 + rr;
    short4 o;
    o.x = f2bs(Lt[cx * 4 + 0][nr]);
    o.y = f2bs(Lt[cx * 4 + 1][nr]);
    o.z = f2bs(Lt[cx * 4 + 2][nr]);
    o.w = f2bs(Lt[cx * 4 + 3][nr]);
    *reinterpret_cast<short4*>(out + (size_t)(n0 + nr) * CC + k0 + cx * 4) = o;
  }
}

// ---------------------------------------------------------------------------
// gemm256<QKV, NBF>: 256 x (NBF*64) tile, BK=64, 8 waves (2M x 4N), 8-phase
// counted-vmcnt schedule (R3/R4-verified ledger, parameterized). Unchanged.
// ---------------------------------------------------------------------------
template<bool QKV, int NBF>
__global__ __launch_bounds__(512, 2)
void gemm256(const short* __restrict__ A, const short* __restrict__ Bt,
             const float* __restrict__ bias,
             short* __restrict__ qb, short* __restrict__ kb, short* __restrict__ vb,
             float* __restrict__ out)
{
  constexpr int BQ   = NBF * 64 * 32;        // elems per B (buf,kc) region
  constexpr int BOFF = 32768;                // A region: [2][2][256][32] elems
  __shared__ __align__(16) short SMEM[BOFF + 4 * BQ];

  const int t = threadIdx.x;
  const int lane = t & 63;
  const int l16 = lane & 15, quad = lane >> 4;
  const int w = t >> 6;
  const int wr = w >> 2, wc = w & 3;            // 2(M) x 4(N) wave grid

  // bijective XCD-chunked block swizzle (nwg % 8 == 0: 384 / 256)
  const int per   = gridDim.x >> 3;
  const int chunk = (blockIdx.x & 7) * per + (blockIdx.x >> 3);
  const int NBC   = QKV ? 12 : (CC / (NBF * 64));
  const int brow  = chunk / NBC, bcol = chunk % NBC;
  const int row0  = brow * 256;
  const int col0  = bcol * (NBF * 64);

  auto stageQA = [&](int bufS, int kcS, int tileS) __attribute__((always_inline)) {
#pragma unroll
    for (int l = 0; l < 2; ++l) {
      int gq = l * 512 + t;
      int rq = gq >> 2;
      int g  = (gq & 3) ^ ((rq >> 1) & 3);
      gl_lds16(A + (size_t)(row0 + rq) * CC + tileS * 64 + kcS * 32 + g * 8,
               &SMEM[bufS * 16384 + kcS * 8192 + gq * 8]);
    }
  };
  auto stageQB = [&](int bufS, int kcS, int tileS) __attribute__((always_inline)) {
#pragma unroll
    for (int l = 0; l < NBF / 2; ++l) {
      int gq = l * 512 + t;
      int rq = gq >> 2;
      int g  = (gq & 3) ^ ((rq >> 1) & 3);
      gl_lds16(Bt + (size_t)(col0 + rq) * CC + tileS * 64 + kcS * 32 + g * 8,
               &SMEM[BOFF + bufS * 2 * BQ + kcS * BQ + gq * 8]);
    }
  };

  f32x4 acc[8][NBF];
#pragma unroll
  for (int i = 0; i < 8; ++i)
#pragma unroll
    for (int j = 0; j < NBF; ++j) acc[i][j] = (f32x4){0.f, 0.f, 0.f, 0.f};

  auto kTile = [&](int u, int cb, int tm) __attribute__((always_inline)) {
    const short* Ac = &SMEM[cb * 16384];
    const short* Bc = &SMEM[BOFF + cb * 2 * BQ];
    short8 bf[NBF];
#pragma unroll
    for (int ph = 0; ph < 4; ++ph) {
      const int kc = ph >> 1, q = ph & 1;
      if (q == 0) {
#pragma unroll
        for (int j = 0; j < NBF; ++j) {
          int rb = wc * (NBF * 16) + j * 16 + l16;
          bf[j] = *reinterpret_cast<const short8*>(
              &Bc[kc * BQ + rb * 32 + (((quad ^ (rb >> 1)) & 3) << 3)]);
        }
      }
      short8 af[4];
#pragma unroll
      for (int iq = 0; iq < 4; ++iq) {
        int ra = wr * 128 + (q * 4 + iq) * 16 + l16;
        af[iq] = *reinterpret_cast<const short8*>(
            &Ac[kc * 8192 + ra * 32 + (((quad ^ (ra >> 1)) & 3) << 3)]);
      }

      if      (ph == 0) { if (tm < 2) stageQA(cb ^ 1, 1, u + 1); }
      else if (ph == 1) { if (tm < 2) stageQB(cb ^ 1, 1, u + 1); }
      else if (ph == 2) { if (tm < 1) stageQA(cb,     0, u + 2); }
      else              { if (tm < 1) stageQB(cb,     0, u + 2); }

      __builtin_amdgcn_s_barrier();
      asm volatile("s_waitcnt lgkmcnt(0)" ::: "memory");
      __builtin_amdgcn_sched_barrier(0);

      __builtin_amdgcn_s_setprio(1);
#pragma unroll
      for (int iq = 0; iq < 4; ++iq)
#pragma unroll
        for (int j = 0; j < NBF; ++j)
          acc[q * 4 + iq][j] =
              __builtin_amdgcn_mfma_f32_16x16x32_bf16(af[iq], bf[j], acc[q * 4 + iq][j], 0, 0, 0);
      __builtin_amdgcn_s_setprio(0);

      if (ph == 1) {
        if (tm == 2) { asm volatile("s_waitcnt vmcnt(0)" ::: "memory"); }
        else if (NBF == 4) { asm volatile("s_waitcnt vmcnt(8)" ::: "memory"); }
        else               { asm volatile("s_waitcnt vmcnt(6)" ::: "memory"); }
      } else if (ph == 3) {
        if (tm == 0) {
          if (NBF == 4) { asm volatile("s_waitcnt vmcnt(8)" ::: "memory"); }
          else          { asm volatile("s_waitcnt vmcnt(6)" ::: "memory"); }
        } else if (tm == 1) {
          if (NBF == 4) { asm volatile("s_waitcnt vmcnt(4)" ::: "memory"); }
          else          { asm volatile("s_waitcnt vmcnt(3)" ::: "memory"); }
        }
      }
      __builtin_amdgcn_s_barrier();
    }
  };

  // prologue: 6 quanta in steady-state issue order
  stageQA(0, 0, 0);  stageQB(0, 0, 0);
  stageQA(0, 1, 0);  stageQB(0, 1, 0);
  stageQA(1, 0, 1);  stageQB(1, 0, 1);
  if (NBF == 4) { asm volatile("s_waitcnt vmcnt(8)" ::: "memory"); }
  else          { asm volatile("s_waitcnt vmcnt(6)" ::: "memory"); }
  __builtin_amdgcn_s_barrier();

  for (int u = 0; u < 14; u += 2) {
    kTile(u,     0, 0);
    kTile(u + 1, 1, 0);
  }
  kTile(14, 0, 1);
  kTile(15, 1, 2);

  if constexpr (QKV) {
    const int sel = col0 >> 10;                    // uniform per block
#pragma unroll
    for (int hp = 0; hp < 2; ++hp) {
      __syncthreads();
      if (wr == hp) {
#pragma unroll
        for (int j = 0; j < 4; ++j) {
          const int colL = wc * 64 + j * 16 + l16;           // 0..255
          const float bv = bias[col0 + colL];
#pragma unroll
          for (int i = 0; i < 8; ++i)
#pragma unroll
            for (int r = 0; r < 4; ++r) {
              const int rl = i * 16 + quad * 4 + r;          // 0..127
              float val = acc[i][j][r] + bv;
              if (sel == 0) val *= QSCALE;
              short vs = f2bs(val);
              if (sel == 2) {
                int tpl = (rl & ~63) | ((rl & 15) << 2) | ((rl >> 4) & 3);
                SMEM[colL * 136 + tpl] = vs;
              } else {
                SMEM[rl * 264 + colL] = vs;
              }
            }
        }
      }
      __syncthreads();
      const int Rbase = row0 + hp * 128;           // 128-aligned -> single bi
      const int bi = Rbase >> 11;
      if (sel == 0) {
        // q: flat [B,H,T,D] (128 B runs)
#pragma unroll
        for (int rep = 0; rep < 8; ++rep) {
          int slot = rep * 512 + t;
          int rl = slot >> 5, ch = slot & 31;
          short8 vv = *reinterpret_cast<const short8*>(&SMEM[rl * 264 + ch * 8]);
          int tt  = (Rbase & 2047) + rl;
          int cin = (col0 + ch * 8) & 1023;
          int hh = cin >> 6, dd = cin & 63;
          *reinterpret_cast<short8*>(
              &qb[(((size_t)(bi * HH + hh)) * TT + tt) * DD + dd]) = vv;
        }
      } else if (sel == 1) {
        // k: 8KB tiles [hb][kt][row=t&63][8 chunk-slots], slot = g ^ ((rt>>1)&7)
#pragma unroll
        for (int rep = 0; rep < 8; ++rep) {
          int slot = rep * 512 + t;
          int rl = slot >> 5, ch = slot & 31;
          short8 vv = *reinterpret_cast<const short8*>(&SMEM[rl * 264 + ch * 8]);
          int tt  = (Rbase & 2047) + rl;
          int cin = (col0 + ch * 8) & 1023;
          int hh = cin >> 6;
          int rt = tt & 63;
          int cs = ((cin >> 3) & 7) ^ ((rt >> 1) & 7);
          size_t tile = (size_t)(bi * HH + hh) * 32 + (tt >> 6);
          *reinterpret_cast<short8*>(&kb[tile * 4096 + rt * 64 + cs * 8]) = vv;
        }
      } else {
        // v: 8KB tiles [hb][kt][row=dd][8 chunk-slots over t-permuted cols]
#pragma unroll
        for (int rep = 0; rep < 8; ++rep) {
          int slot = rep * 512 + t;
          int dcol = slot >> 4, ch = slot & 15;
          short8 vv = *reinterpret_cast<const short8*>(&SMEM[dcol * 136 + ch * 8]);
          int cin = (col0 + dcol) & 1023;
          int hh = cin >> 6, dd = cin & 63;
          int ktv = ((Rbase & 2047) >> 6) + (ch >> 3);
          int cs  = (ch & 7) ^ ((dd >> 1) & 7);
          *reinterpret_cast<short8*>(
              &vb[((size_t)(bi * HH + hh) * 32 + ktv) * 4096 + dd * 64 + cs * 8]) = vv;
        }
      }
    }
  } else {
#pragma unroll
    for (int j = 0; j < NBF; ++j) {
      int col = col0 + wc * (NBF * 16) + j * 16 + l16;
      float bv = bias[col];
#pragma unroll
      for (int i = 0; i < 8; ++i)
#pragma unroll
        for (int r = 0; r < 4; ++r) {
          int row = row0 + wr * 128 + i * 16 + quad * 4 + r;
          out[(size_t)row * CC + col] = acc[i][j][r] + bv;
        }
    }
  }
}

// ---------------------------------------------------------------------------
// K2: MFMA flash attention, 32 q-rows per wave (2x16 sub-blocks).
// Rationale (R6 PMC): attn was LDS-read-throughput bound — 18 wave-b128
// K/V fragment reads per wave-iter fed only 16 MFMA. Doubling rows/wave
// halves LDS bytes per FLOP: same 16 fragment reads now feed 32 MFMA.
// Block = 4 waves x 32 rows = 128 q-rows; grid halves to 512 blocks
// (2/CU at 42.4 KB LDS). Q-block pairing {qb, 15-qb} keeps 34 balanced
// k-iterations per block. Staging ledger identical to R6 (verified):
//   prologue K(0),V(0),K(1), vmcnt(4) [qf(4)+K0(2) certified] ; barrier
//   iter: QK^T; softmax->Pw; vmcnt(0); barrier1; stageK(kt+2);
//         PV; barrier2; stageV(kt+1)
// ---------------------------------------------------------------------------
__global__ __launch_bounds__(256, 2)
void attn_mfma(const short* __restrict__ Qb, const short* __restrict__ Kb,
               const short* __restrict__ Vb, short* __restrict__ Y)
{
  __shared__ __align__(16) short Kd[2][4096];
  __shared__ __align__(16) short Vt[4096];
  __shared__ __align__(16) short Pw[4 * 32 * LDST];

  const int t    = threadIdx.x;
  const int w    = t >> 6;
  const int lane = t & 63;
  const int l16  = lane & 15;
  const int quad = lane >> 4;

  // XCD-chunked bijective remap: 512 blocks -> XCD k owns nb in [64k,64k+64)
  const int linear = blockIdx.x + 8 * (blockIdx.y + 16 * blockIdx.z);
  const int nb  = (linear & 7) * 64 + (linear >> 3);
  const int qb0 = nb & 7;          // q-block pair id 0..7
  const int h   = (nb >> 3) & 15;
  const int bi  = nb >> 7;
  const size_t head = (size_t)(bi * HH + h) * TT * DD;   // == tile_base*4096

  short* myP = &Pw[w * 32 * LDST];

  auto stageK = [&](int kt, int p) __attribute__((always_inline)) {
    const short* src = Kb + head + (size_t)kt * 4096;
    gl_lds16(src + t * 8,        &Kd[p][t * 8]);
    gl_lds16(src + 2048 + t * 8, &Kd[p][2048 + t * 8]);
  };
  auto stageV = [&](int kt) __attribute__((always_inline)) {
    const short* src = Vb + head + (size_t)kt * 4096;
    gl_lds16(src + t * 8,        &Vt[t * 8]);
    gl_lds16(src + 2048 + t * 8, &Vt[2048 + t * 8]);
  };

  const int qbs[2] = { qb0, 15 - qb0 };

#pragma unroll
  for (int half = 0; half < 2; ++half) {
    const int qb  = qbs[half];
    const int q0  = qb * 128;
    const int nkt = 2 * qb + 2;     // k-tiles 0 .. 2qb+1 (>=2 always)

    short8 qf[2][2];
#pragma unroll
    for (int i = 0; i < 2; ++i)
#pragma unroll
      for (int kc = 0; kc < 2; ++kc)
        qf[i][kc] = *reinterpret_cast<const short8*>(
            &Qb[head + (size_t)(q0 + w * 32 + i * 16 + l16) * DD + kc * 32 + quad * 8]);

    f32x4 O[2][4];
#pragma unroll
    for (int i = 0; i < 2; ++i)
#pragma unroll
      for (int dt = 0; dt < 4; ++dt) O[i][dt] = (f32x4){0.f, 0.f, 0.f, 0.f};
    float lsum[2][4] = {};

    // prologue: K(0), V(0), K(1); certify qf + K(0) (keep V(0),K(1) in flight)
    stageK(0, 0);
    stageV(0);
    stageK(1, 1);
    asm volatile("s_waitcnt vmcnt(4)" ::: "memory");
    __builtin_amdgcn_s_barrier();

    for (int kt = 0; kt < nkt; ++kt) {
      const int p  = kt & 1;
      const int k0 = kt * 64;

      // QK^T from Kd[p] (8 shared K-frag reads feed 16 MFMA)
      short8 kf[4][2];
#pragma unroll
      for (int nt = 0; nt < 4; ++nt)
#pragma unroll
        for (int kc = 0; kc < 2; ++kc) {
          int r = nt * 16 + l16;
          int c = kc * 4 + quad;
          kf[nt][kc] = *reinterpret_cast<const short8*>(
              &Kd[p][r * 64 + ((c ^ ((r >> 1) & 7)) << 3)]);
        }

      f32x4 s[2][4];
#pragma unroll
      for (int i = 0; i < 2; ++i)
#pragma unroll
        for (int nt = 0; nt < 4; ++nt) s[i][nt] = (f32x4){0.f, 0.f, 0.f, 0.f};
      __builtin_amdgcn_s_setprio(1);
#pragma unroll
      for (int i = 0; i < 2; ++i)
#pragma unroll
        for (int nt = 0; nt < 4; ++nt)
#pragma unroll
          for (int kc = 0; kc < 2; ++kc)
            s[i][nt] = __builtin_amdgcn_mfma_f32_16x16x32_bf16(qf[i][kc], kf[nt][kc], s[i][nt], 0, 0, 0);
      __builtin_amdgcn_s_setprio(0);

#pragma unroll
      for (int i = 0; i < 2; ++i) {
        const int rowg_base = q0 + w * 32 + i * 16 + quad * 4;
#pragma unroll
        for (int r = 0; r < 4; ++r) {
          const int rowg = rowg_base + r;
          short pk[4];
#pragma unroll
          for (int nt = 0; nt < 4; ++nt) {
            float e = (k0 + nt * 16 + l16 <= rowg) ? __builtin_amdgcn_exp2f(s[i][nt][r]) : 0.f;
            lsum[i][r] += e;
            pk[nt] = f2bs(e);
          }
          short4 p4; p4.x = pk[0]; p4.y = pk[1]; p4.z = pk[2]; p4.w = pk[3];
          *reinterpret_cast<short4*>(&myP[(i * 16 + quad * 4 + r) * LDST + (l16 << 2)]) = p4;
        }
      }

      asm volatile("s_waitcnt vmcnt(0)" ::: "memory");  // V(kt), K(kt+1) landed
      __builtin_amdgcn_s_barrier();                     // barrier1 (block-wide)

      if (kt + 2 < nkt) stageK(kt + 2, p);              // Kd[p] free after barrier1

      __builtin_amdgcn_s_setprio(1);
#pragma unroll
      for (int cc = 0; cc < 2; ++cc) {
        short8 pf[2];
#pragma unroll
        for (int i = 0; i < 2; ++i)
          pf[i] = *reinterpret_cast<const short8*>(
              &myP[(i * 16 + l16) * LDST + cc * 32 + quad * 8]);
#pragma unroll
        for (int dt = 0; dt < 4; ++dt) {
          int r = dt * 16 + l16;
          int c = cc * 4 + quad;
          short8 vf = *reinterpret_cast<const short8*>(
              &Vt[r * 64 + ((c ^ ((r >> 1) & 7)) << 3)]);
#pragma unroll
          for (int i = 0; i < 2; ++i)
            O[i][dt] = __builtin_amdgcn_mfma_f32_16x16x32_bf16(pf[i], vf, O[i][dt], 0, 0, 0);
        }
      }
      __builtin_amdgcn_s_setprio(0);

      __builtin_amdgcn_s_barrier();                     // barrier2: Vt free
      if (kt + 1 < nkt) stageV(kt + 1);
    }

    float linv[2][4];
#pragma unroll
    for (int i = 0; i < 2; ++i)
#pragma unroll
      for (int r = 0; r < 4; ++r) {
        float s = lsum[i][r];
        s += __shfl_xor(s, 1);
        s += __shfl_xor(s, 2);
        s += __shfl_xor(s, 4);
        s += __shfl_xor(s, 8);
        linv[i][r] = 1.f / s;
      }
#pragma unroll
    for (int i = 0; i < 2; ++i)
#pragma unroll
      for (int dt = 0; dt < 4; ++dt)
#pragma unroll
        for (int r = 0; r < 4; ++r) {
          int tg = q0 + w * 32 + i * 16 + quad * 4 + r;
          Y[((size_t)bi * TT + tg) * CC + h * DD + dt * 16 + l16] =
              f2bs(O[i][dt][r] * linv[i][r]);
        }
  }
}

// ---------------------------------------------------------------------------
extern "C" void kernel_launch(void* const* d_in, const int* in_sizes, int n_in,
                              void* d_out, int out_size, void* d_ws, size_t ws_size,
                              hipStream_t stream) {
  const float* x  = (const float*)d_in[0];   // [4,2048,1024] fp32
  const float* Wa = (const float*)d_in[1];   // [1024,3072]  fp32
  const float* ba = (const float*)d_in[2];   // [3072]       fp32
  const float* Wp = (const float*)d_in[3];   // [1024,1024]  fp32
  const float* bp = (const float*)d_in[4];   // [1024]       fp32
  float* out = (float*)d_out;                // [4,2048,1024] fp32

  const size_t NELT = (size_t)BB * HH * TT * DD;   // 8388608
  short* qb  = (short*)d_ws;                       // bf16 [B,H,T,D] (pre-scaled)
  short* kb  = qb + NELT;                          // bf16 tiles [B*H][32][64][64] swz
  short* vb  = kb + NELT;                          // bf16 tiles [B*H][32][64][64] swz
  short* Xb  = vb + NELT;                          // [8192][1024] bf16
  short* Wat = Xb  + (size_t)BT * CC;              // [3072][1024] bf16 (Wa^T)
  short* Wpt = Wat + (size_t)CC * C3;              // [1024][1024] bf16 (Wp^T)
  short* Yb  = Wpt + (size_t)CC * CC;              // [8192][1024] bf16

  prep<<<dim3(64 + 256, 16), 256, 0, stream>>>(Wa, Wat, Wp, Wpt, x, Xb);

  gemm256<true, 4> <<<dim3((C3 / 256) * (BT / 256)), 512, 0, stream>>>(Xb, Wat, ba, qb, kb, vb, nullptr);
  attn_mfma        <<<dim3(8, HH, BB),               256, 0, stream>>>(qb, kb, vb, Yb);
  gemm256<false, 2><<<dim3((CC / 128) * (BT / 256)), 512, 0, stream>>>(Yb, Wpt, bp, nullptr, nullptr, nullptr, out);
}

// Round 8
// 241.728 us; speedup vs baseline: 1.0515x; 1.0515x over previous
//
#include <hip/hip_runtime.h>
#include <hip/hip_bf16.h>

#define BB 4
#define TT 2048
#define CC 1024
#define HH 16
#define DD 64
#define BT (BB*TT)   // 8192
#define C3 (3*CC)    // 3072
#define LDST 72      // attn P-buffer row stride in bf16 elems (144 B)
#define QSCALE 0.18033688011112042f   // 0.125 * log2(e)

typedef __attribute__((ext_vector_type(8))) short short8;
typedef __attribute__((ext_vector_type(4))) float f32x4;

__device__ __forceinline__ short f2bs(float f) {
  __hip_bfloat16 h = __float2bfloat16(f);
  return *reinterpret_cast<short*>(&h);
}

__device__ __forceinline__ void gl_lds16(const short* g, short* l) {
  __builtin_amdgcn_global_load_lds(
      (const __attribute__((address_space(1))) void*)(g),
      (__attribute__((address_space(3))) void*)(l), 16, 0, 0);
}

// ---------------------------------------------------------------------------
// P: single prep launch (verified R8, unchanged).
// ---------------------------------------------------------------------------
__global__ __launch_bounds__(256)
void prep(const float* __restrict__ Wa, short* __restrict__ Wat,
          const float* __restrict__ Wp, short* __restrict__ Wpt,
          const float* __restrict__ x, short* __restrict__ Xb)
{
  __shared__ float Lt[64][65];
  const int bx = blockIdx.x;
  if (bx >= 64) {
    size_t chunk = (size_t)(bx - 64) * 16 + blockIdx.y;
    size_t i = (chunk * 256 + threadIdx.x) * 8;
    float4 a = *reinterpret_cast<const float4*>(x + i);
    float4 b = *reinterpret_cast<const float4*>(x + i + 4);
    short8 o;
    o[0] = f2bs(a.x); o[1] = f2bs(a.y); o[2] = f2bs(a.z); o[3] = f2bs(a.w);
    o[4] = f2bs(b.x); o[5] = f2bs(b.y); o[6] = f2bs(b.z); o[7] = f2bs(b.w);
    *reinterpret_cast<short8*>(Xb + i) = o;
    return;
  }
  const bool isA = (bx < 48);
  const float* in  = isA ? Wa  : Wp;
  short*       out = isA ? Wat : Wpt;
  const int N  = isA ? C3 : CC;
  const int n0 = (isA ? bx : bx - 48) * 64;
  const int k0 = blockIdx.y * 64;
  const int cx = threadIdx.x & 15, rr = threadIdx.x >> 4;
#pragma unroll
  for (int p = 0; p < 4; ++p) {
    int kr = p * 16 + rr;
    float4 u = *reinterpret_cast<const float4*>(in + (size_t)(k0 + kr) * N + n0 + cx * 4);
    Lt[kr][cx * 4 + 0] = u.x;
    Lt[kr][cx * 4 + 1] = u.y;
    Lt[kr][cx * 4 + 2] = u.z;
    Lt[kr][cx * 4 + 3] = u.w;
  }
  __syncthreads();
#pragma unroll
  for (int p = 0; p < 4; ++p) {
    int nr = p * 16 + rr;
    short4 o;
    o.x = f2bs(Lt[cx * 4 + 0][nr]);
    o.y = f2bs(Lt[cx * 4 + 1][nr]);
    o.z = f2bs(Lt[cx * 4 + 2][nr]);
    o.w = f2bs(Lt[cx * 4 + 3][nr]);
    *reinterpret_cast<short4*>(out + (size_t)(n0 + nr) * CC + k0 + cx * 4) = o;
  }
}

// ---------------------------------------------------------------------------
// gemm128<QKV>: 128x128 tile, BK=64, 4 waves (2M x 2N, 64x64 each),
// 64 KB LDS -> 2 blocks/CU (the TLP fix: R7 showed the 256² 1-block/CU
// schedule is barrier-serialized — 2 co-resident blocks fill each other's
// barrier/drain stalls).  Same verified 4-phase/tile counted-vmcnt ledger
// as R3-R7 (stage quanta are still exactly 2 loads/thread, so the
// vmcnt(8)/(4)/(0) constants are unchanged), same conflict-free swizzle,
// same LDS-bounce epilogue (tiles for attn baked at rest).
// Grids perfectly balanced at 2/CU: qkv 64x24=1536 = 3 exact rounds,
// proj 64x8=512 = 1 exact round.
// ---------------------------------------------------------------------------
template<bool QKV>
__global__ __launch_bounds__(256, 2)
void gemm128(const short* __restrict__ A, const short* __restrict__ Bt,
             const float* __restrict__ bias,
             short* __restrict__ qb, short* __restrict__ kb, short* __restrict__ vb,
             float* __restrict__ out)
{
  // A: [2 buf][2 kc][128][32] = 16384 shorts; B same at +16384. 64 KB total.
  __shared__ __align__(16) short SMEM[32768];

  const int t = threadIdx.x;
  const int lane = t & 63;
  const int l16 = lane & 15, quad = lane >> 4;
  const int w = t >> 6;
  const int wm = w & 1, wn = w >> 1;            // 2(M) x 2(N) wave grid

  // bijective XCD-chunked block swizzle (1536 % 8 == 0, 512 % 8 == 0)
  const int per   = gridDim.x >> 3;
  const int chunk = (blockIdx.x & 7) * per + (blockIdx.x >> 3);
  const int NBC   = QKV ? 24 : 8;
  const int row0  = (chunk / NBC) * 128;
  const int col0  = (chunk % NBC) * 128;

  auto stageQA = [&](int bufS, int kcS, int tileS) __attribute__((always_inline)) {
#pragma unroll
    for (int l = 0; l < 2; ++l) {
      int gq = l * 256 + t;                 // 16B-chunk id 0..511
      int rq = gq >> 2;                     // row 0..127
      int g  = (gq & 3) ^ ((rq >> 1) & 3);  // conflict-free involution
      gl_lds16(A + (size_t)(row0 + rq) * CC + tileS * 64 + kcS * 32 + g * 8,
               &SMEM[bufS * 8192 + kcS * 4096 + gq * 8]);
    }
  };
  auto stageQB = [&](int bufS, int kcS, int tileS) __attribute__((always_inline)) {
#pragma unroll
    for (int l = 0; l < 2; ++l) {
      int gq = l * 256 + t;
      int rq = gq >> 2;
      int g  = (gq & 3) ^ ((rq >> 1) & 3);
      gl_lds16(Bt + (size_t)(col0 + rq) * CC + tileS * 64 + kcS * 32 + g * 8,
               &SMEM[16384 + bufS * 8192 + kcS * 4096 + gq * 8]);
    }
  };

  f32x4 acc[4][4];
#pragma unroll
  for (int i = 0; i < 4; ++i)
#pragma unroll
    for (int j = 0; j < 4; ++j) acc[i][j] = (f32x4){0.f, 0.f, 0.f, 0.f};

  // tm: 0=steady, 1=u14 (stage ph0/1 only, ph3 vmcnt4), 2=u15 (no stages,
  // ph1 vmcnt0). Ledger identical to R3-R7 (2-load quanta).
  auto kTile = [&](int u, int cb, int tm) __attribute__((always_inline)) {
    const short* Ac = &SMEM[cb * 8192];
    const short* Bc = &SMEM[16384 + cb * 8192];
    short8 bf[4];
#pragma unroll
    for (int ph = 0; ph < 4; ++ph) {
      const int kc = ph >> 1, q = ph & 1;
      if (q == 0) {
#pragma unroll
        for (int j = 0; j < 4; ++j) {
          int rb = wn * 64 + j * 16 + l16;
          bf[j] = *reinterpret_cast<const short8*>(
              &Bc[kc * 4096 + rb * 32 + (((quad ^ (rb >> 1)) & 3) << 3)]);
        }
      }
      short8 af[2];
#pragma unroll
      for (int iq = 0; iq < 2; ++iq) {
        int ra = wm * 64 + (q * 2 + iq) * 16 + l16;
        af[iq] = *reinterpret_cast<const short8*>(
            &Ac[kc * 4096 + ra * 32 + (((quad ^ (ra >> 1)) & 3) << 3)]);
      }

      if      (ph == 0) { if (tm < 2) stageQA(cb ^ 1, 1, u + 1); }
      else if (ph == 1) { if (tm < 2) stageQB(cb ^ 1, 1, u + 1); }
      else if (ph == 2) { if (tm < 1) stageQA(cb,     0, u + 2); }
      else              { if (tm < 1) stageQB(cb,     0, u + 2); }

      __builtin_amdgcn_s_barrier();
      asm volatile("s_waitcnt lgkmcnt(0)" ::: "memory");
      __builtin_amdgcn_sched_barrier(0);

      __builtin_amdgcn_s_setprio(1);
#pragma unroll
      for (int iq = 0; iq < 2; ++iq)
#pragma unroll
        for (int j = 0; j < 4; ++j)
          acc[q * 2 + iq][j] =
              __builtin_amdgcn_mfma_f32_16x16x32_bf16(af[iq], bf[j], acc[q * 2 + iq][j], 0, 0, 0);
      __builtin_amdgcn_s_setprio(0);

      if (ph == 1) {
        if (tm == 2) { asm volatile("s_waitcnt vmcnt(0)" ::: "memory"); }
        else         { asm volatile("s_waitcnt vmcnt(8)" ::: "memory"); }
      } else if (ph == 3) {
        if      (tm == 0) { asm volatile("s_waitcnt vmcnt(8)" ::: "memory"); }
        else if (tm == 1) { asm volatile("s_waitcnt vmcnt(4)" ::: "memory"); }
      }
      __builtin_amdgcn_s_barrier();
    }
  };

  // prologue: 6 quanta (12 loads); vmcnt(8) certifies A.kc0(0)+B.kc0(0)
  stageQA(0, 0, 0);  stageQB(0, 0, 0);
  stageQA(0, 1, 0);  stageQB(0, 1, 0);
  stageQA(1, 0, 1);  stageQB(1, 0, 1);
  asm volatile("s_waitcnt vmcnt(8)" ::: "memory");
  __builtin_amdgcn_s_barrier();

  for (int u = 0; u < 14; u += 2) {
    kTile(u,     0, 0);
    kTile(u + 1, 1, 0);
  }
  kTile(14, 0, 1);
  kTile(15, 1, 2);

  if constexpr (QKV) {
    const int sel = col0 >> 10;                    // uniform per block
    const int bi  = row0 >> 11;
    // write pass: all 4 waves dump acc into the bounce tile (stride 136)
#pragma unroll
    for (int j = 0; j < 4; ++j) {
      const int colL = wn * 64 + j * 16 + l16;           // 0..127
      const float bv = bias[col0 + colL];
#pragma unroll
      for (int i = 0; i < 4; ++i)
#pragma unroll
        for (int r = 0; r < 4; ++r) {
          const int rl = wm * 64 + i * 16 + quad * 4 + r; // 0..127
          float val = acc[i][j][r] + bv;
          if (sel == 0) val *= QSCALE;
          short vs = f2bs(val);
          if (sel == 2) {
            int tpl = (rl & ~63) | ((rl & 15) << 2) | ((rl >> 4) & 3);
            SMEM[colL * 136 + tpl] = vs;
          } else {
            SMEM[rl * 136 + colL] = vs;
          }
        }
    }
    __syncthreads();
    if (sel == 0) {
      // q: flat [B,H,T,D] (128 B runs)
#pragma unroll
      for (int rep = 0; rep < 8; ++rep) {
        int slot = rep * 256 + t;
        int rl = slot >> 4, ch = slot & 15;
        short8 vv = *reinterpret_cast<const short8*>(&SMEM[rl * 136 + ch * 8]);
        int tt  = (row0 & 2047) + rl;
        int cin = (col0 + ch * 8) & 1023;
        int hh = cin >> 6, dd = cin & 63;
        *reinterpret_cast<short8*>(
            &qb[(((size_t)(bi * HH + hh)) * TT + tt) * DD + dd]) = vv;
      }
    } else if (sel == 1) {
      // k: 8KB tiles [hb][kt][row=t&63][slot], slot = g ^ ((rt>>1)&7)
#pragma unroll
      for (int rep = 0; rep < 8; ++rep) {
        int slot = rep * 256 + t;
        int rl = slot >> 4, ch = slot & 15;
        short8 vv = *reinterpret_cast<const short8*>(&SMEM[rl * 136 + ch * 8]);
        int tt  = (row0 & 2047) + rl;
        int cin = (col0 + ch * 8) & 1023;
        int hh = cin >> 6;
        int rt = tt & 63;
        int cs = ((cin >> 3) & 7) ^ ((rt >> 1) & 7);
        size_t tile = (size_t)(bi * HH + hh) * 32 + (tt >> 6);
        *reinterpret_cast<short8*>(&kb[tile * 4096 + rt * 64 + cs * 8]) = vv;
      }
    } else {
      // v: 8KB tiles [hb][kt][row=dd][slot over t-permuted cols]
#pragma unroll
      for (int rep = 0; rep < 8; ++rep) {
        int slot = rep * 256 + t;
        int dcol = slot >> 4, ch = slot & 15;
        short8 vv = *reinterpret_cast<const short8*>(&SMEM[dcol * 136 + ch * 8]);
        int cin = (col0 + dcol) & 1023;
        int hh = cin >> 6, dd = cin & 63;
        int ktv = ((row0 & 2047) >> 6) + (ch >> 3);
        int cs  = (ch & 7) ^ ((dd >> 1) & 7);
        *reinterpret_cast<short8*>(
            &vb[((size_t)(bi * HH + hh) * 32 + ktv) * 4096 + dd * 64 + cs * 8]) = vv;
      }
    }
  } else {
#pragma unroll
    for (int j = 0; j < 4; ++j) {
      int col = col0 + wn * 64 + j * 16 + l16;
      float bv = bias[col];
#pragma unroll
      for (int i = 0; i < 4; ++i)
#pragma unroll
        for (int r = 0; r < 4; ++r) {
          int row = row0 + wm * 64 + i * 16 + quad * 4 + r;
          out[(size_t)row * CC + col] = acc[i][j][r] + bv;
        }
    }
  }
}

// ---------------------------------------------------------------------------
// K2: MFMA flash attention, 32 q-rows per wave (R7 body, unchanged — it
// delivered 132 -> ~84 µs).
// ---------------------------------------------------------------------------
__global__ __launch_bounds__(256, 2)
void attn_mfma(const short* __restrict__ Qb, const short* __restrict__ Kb,
               const short* __restrict__ Vb, short* __restrict__ Y)
{
  __shared__ __align__(16) short Kd[2][4096];
  __shared__ __align__(16) short Vt[4096];
  __shared__ __align__(16) short Pw[4 * 32 * LDST];

  const int t    = threadIdx.x;
  const int w    = t >> 6;
  const int lane = t & 63;
  const int l16  = lane & 15;
  const int quad = lane >> 4;

  // XCD-chunked bijective remap: 512 blocks -> XCD k owns nb in [64k,64k+64)
  const int linear = blockIdx.x + 8 * (blockIdx.y + 16 * blockIdx.z);
  const int nb  = (linear & 7) * 64 + (linear >> 3);
  const int qb0 = nb & 7;          // q-block pair id 0..7
  const int h   = (nb >> 3) & 15;
  const int bi  = nb >> 7;
  const size_t head = (size_t)(bi * HH + h) * TT * DD;   // == tile_base*4096

  short* myP = &Pw[w * 32 * LDST];

  auto stageK = [&](int kt, int p) __attribute__((always_inline)) {
    const short* src = Kb + head + (size_t)kt * 4096;
    gl_lds16(src + t * 8,        &Kd[p][t * 8]);
    gl_lds16(src + 2048 + t * 8, &Kd[p][2048 + t * 8]);
  };
  auto stageV = [&](int kt) __attribute__((always_inline)) {
    const short* src = Vb + head + (size_t)kt * 4096;
    gl_lds16(src + t * 8,        &Vt[t * 8]);
    gl_lds16(src + 2048 + t * 8, &Vt[2048 + t * 8]);
  };

  const int qbs[2] = { qb0, 15 - qb0 };

#pragma unroll
  for (int half = 0; half < 2; ++half) {
    const int qb  = qbs[half];
    const int q0  = qb * 128;
    const int nkt = 2 * qb + 2;     // k-tiles 0 .. 2qb+1 (>=2 always)

    short8 qf[2][2];
#pragma unroll
    for (int i = 0; i < 2; ++i)
#pragma unroll
      for (int kc = 0; kc < 2; ++kc)
        qf[i][kc] = *reinterpret_cast<const short8*>(
            &Qb[head + (size_t)(q0 + w * 32 + i * 16 + l16) * DD + kc * 32 + quad * 8]);

    f32x4 O[2][4];
#pragma unroll
    for (int i = 0; i < 2; ++i)
#pragma unroll
      for (int dt = 0; dt < 4; ++dt) O[i][dt] = (f32x4){0.f, 0.f, 0.f, 0.f};
    float lsum[2][4] = {};

    // prologue: K(0), V(0), K(1); certify qf + K(0)
    stageK(0, 0);
    stageV(0);
    stageK(1, 1);
    asm volatile("s_waitcnt vmcnt(4)" ::: "memory");
    __builtin_amdgcn_s_barrier();

    for (int kt = 0; kt < nkt; ++kt) {
      const int p  = kt & 1;
      const int k0 = kt * 64;

      short8 kf[4][2];
#pragma unroll
      for (int nt = 0; nt < 4; ++nt)
#pragma unroll
        for (int kc = 0; kc < 2; ++kc) {
          int r = nt * 16 + l16;
          int c = kc * 4 + quad;
          kf[nt][kc] = *reinterpret_cast<const short8*>(
              &Kd[p][r * 64 + ((c ^ ((r >> 1) & 7)) << 3)]);
        }

      f32x4 s[2][4];
#pragma unroll
      for (int i = 0; i < 2; ++i)
#pragma unroll
        for (int nt = 0; nt < 4; ++nt) s[i][nt] = (f32x4){0.f, 0.f, 0.f, 0.f};
      __builtin_amdgcn_s_setprio(1);
#pragma unroll
      for (int i = 0; i < 2; ++i)
#pragma unroll
        for (int nt = 0; nt < 4; ++nt)
#pragma unroll
          for (int kc = 0; kc < 2; ++kc)
            s[i][nt] = __builtin_amdgcn_mfma_f32_16x16x32_bf16(qf[i][kc], kf[nt][kc], s[i][nt], 0, 0, 0);
      __builtin_amdgcn_s_setprio(0);

#pragma unroll
      for (int i = 0; i < 2; ++i) {
        const int rowg_base = q0 + w * 32 + i * 16 + quad * 4;
#pragma unroll
        for (int r = 0; r < 4; ++r) {
          const int rowg = rowg_base + r;
          short pk[4];
#pragma unroll
          for (int nt = 0; nt < 4; ++nt) {
            float e = (k0 + nt * 16 + l16 <= rowg) ? __builtin_amdgcn_exp2f(s[i][nt][r]) : 0.f;
            lsum[i][r] += e;
            pk[nt] = f2bs(e);
          }
          short4 p4; p4.x = pk[0]; p4.y = pk[1]; p4.z = pk[2]; p4.w = pk[3];
          *reinterpret_cast<short4*>(&myP[(i * 16 + quad * 4 + r) * LDST + (l16 << 2)]) = p4;
        }
      }

      asm volatile("s_waitcnt vmcnt(0)" ::: "memory");  // V(kt), K(kt+1) landed
      __builtin_amdgcn_s_barrier();                     // barrier1 (block-wide)

      if (kt + 2 < nkt) stageK(kt + 2, p);              // Kd[p] free after barrier1

      __builtin_amdgcn_s_setprio(1);
#pragma unroll
      for (int cc = 0; cc < 2; ++cc) {
        short8 pf[2];
#pragma unroll
        for (int i = 0; i < 2; ++i)
          pf[i] = *reinterpret_cast<const short8*>(
              &myP[(i * 16 + l16) * LDST + cc * 32 + quad * 8]);
#pragma unroll
        for (int dt = 0; dt < 4; ++dt) {
          int r = dt * 16 + l16;
          int c = cc * 4 + quad;
          short8 vf = *reinterpret_cast<const short8*>(
              &Vt[r * 64 + ((c ^ ((r >> 1) & 7)) << 3)]);
#pragma unroll
          for (int i = 0; i < 2; ++i)
            O[i][dt] = __builtin_amdgcn_mfma_f32_16x16x32_bf16(pf[i], vf, O[i][dt], 0, 0, 0);
        }
      }
      __builtin_amdgcn_s_setprio(0);

      __builtin_amdgcn_s_barrier();                     // barrier2: Vt free
      if (kt + 1 < nkt) stageV(kt + 1);
    }

    float linv[2][4];
#pragma unroll
    for (int i = 0; i < 2; ++i)
#pragma unroll
      for (int r = 0; r < 4; ++r) {
        float s = lsum[i][r];
        s += __shfl_xor(s, 1);
        s += __shfl_xor(s, 2);
        s += __shfl_xor(s, 4);
        s += __shfl_xor(s, 8);
        linv[i][r] = 1.f / s;
      }
#pragma unroll
    for (int i = 0; i < 2; ++i)
#pragma unroll
      for (int dt = 0; dt < 4; ++dt)
#pragma unroll
        for (int r = 0; r < 4; ++r) {
          int tg = q0 + w * 32 + i * 16 + quad * 4 + r;
          Y[((size_t)bi * TT + tg) * CC + h * DD + dt * 16 + l16] =
              f2bs(O[i][dt][r] * linv[i][r]);
        }
  }
}

// ---------------------------------------------------------------------------
extern "C" void kernel_launch(void* const* d_in, const int* in_sizes, int n_in,
                              void* d_out, int out_size, void* d_ws, size_t ws_size,
                              hipStream_t stream) {
  const float* x  = (const float*)d_in[0];   // [4,2048,1024] fp32
  const float* Wa = (const float*)d_in[1];   // [1024,3072]  fp32
  const float* ba = (const float*)d_in[2];   // [3072]       fp32
  const float* Wp = (const float*)d_in[3];   // [1024,1024]  fp32
  const float* bp = (const float*)d_in[4];   // [1024]       fp32
  float* out = (float*)d_out;                // [4,2048,1024] fp32

  const size_t NELT = (size_t)BB * HH * TT * DD;   // 8388608
  short* qb  = (short*)d_ws;                       // bf16 [B,H,T,D] (pre-scaled)
  short* kb  = qb + NELT;                          // bf16 tiles [B*H][32][64][64] swz
  short* vb  = kb + NELT;                          // bf16 tiles [B*H][32][64][64] swz
  short* Xb  = vb + NELT;                          // [8192][1024] bf16
  short* Wat = Xb  + (size_t)BT * CC;              // [3072][1024] bf16 (Wa^T)
  short* Wpt = Wat + (size_t)CC * C3;              // [1024][1024] bf16 (Wp^T)
  short* Yb  = Wpt + (size_t)CC * CC;              // [8192][1024] bf16

  prep<<<dim3(64 + 256, 16), 256, 0, stream>>>(Wa, Wat, Wp, Wpt, x, Xb);

  gemm128<true> <<<dim3((BT / 128) * (C3 / 128)), 256, 0, stream>>>(Xb, Wat, ba, qb, kb, vb, nullptr);
  attn_mfma     <<<dim3(8, HH, BB),               256, 0, stream>>>(qb, kb, vb, Yb);
  gemm128<false><<<dim3((BT / 128) * (CC / 128)), 256, 0, stream>>>(Yb, Wpt, bp, nullptr, nullptr, nullptr, out);
}

// Round 9
// 232.910 us; speedup vs baseline: 1.0913x; 1.0379x over previous
//
#include <hip/hip_runtime.h>
#include <hip/hip_bf16.h>

#define BB 4
#define TT 2048
#define CC 1024
#define HH 16
#define DD 64
#define BT (BB*TT)   // 8192
#define C3 (3*CC)    // 3072
#define LDST 72      // attn P-buffer row stride in bf16 elems (144 B)
#define QSCALE 0.18033688011112042f   // 0.125 * log2(e)

typedef __attribute__((ext_vector_type(8))) short short8;
typedef __attribute__((ext_vector_type(4))) float f32x4;

__device__ __forceinline__ short f2bs(float f) {
  __hip_bfloat16 h = __float2bfloat16(f);
  return *reinterpret_cast<short*>(&h);
}

__device__ __forceinline__ void gl_lds16(const short* g, short* l) {
  __builtin_amdgcn_global_load_lds(
      (const __attribute__((address_space(1))) void*)(g),
      (__attribute__((address_space(3))) void*)(l), 16, 0, 0);
}

// ---------------------------------------------------------------------------
// P: single prep launch (verified, unchanged).
// ---------------------------------------------------------------------------
__global__ __launch_bounds__(256)
void prep(const float* __restrict__ Wa, short* __restrict__ Wat,
          const float* __restrict__ Wp, short* __restrict__ Wpt,
          const float* __restrict__ x, short* __restrict__ Xb)
{
  __shared__ float Lt[64][65];
  const int bx = blockIdx.x;
  if (bx >= 64) {
    size_t chunk = (size_t)(bx - 64) * 16 + blockIdx.y;
    size_t i = (chunk * 256 + threadIdx.x) * 8;
    float4 a = *reinterpret_cast<const float4*>(x + i);
    float4 b = *reinterpret_cast<const float4*>(x + i + 4);
    short8 o;
    o[0] = f2bs(a.x); o[1] = f2bs(a.y); o[2] = f2bs(a.z); o[3] = f2bs(a.w);
    o[4] = f2bs(b.x); o[5] = f2bs(b.y); o[6] = f2bs(b.z); o[7] = f2bs(b.w);
    *reinterpret_cast<short8*>(Xb + i) = o;
    return;
  }
  const bool isA = (bx < 48);
  const float* in  = isA ? Wa  : Wp;
  short*       out = isA ? Wat : Wpt;
  const int N  = isA ? C3 : CC;
  const int n0 = (isA ? bx : bx - 48) * 64;
  const int k0 = blockIdx.y * 64;
  const int cx = threadIdx.x & 15, rr = threadIdx.x >> 4;
#pragma unroll
  for (int p = 0; p < 4; ++p) {
    int kr = p * 16 + rr;
    float4 u = *reinterpret_cast<const float4*>(in + (size_t)(k0 + kr) * N + n0 + cx * 4);
    Lt[kr][cx * 4 + 0] = u.x;
    Lt[kr][cx * 4 + 1] = u.y;
    Lt[kr][cx * 4 + 2] = u.z;
    Lt[kr][cx * 4 + 3] = u.w;
  }
  __syncthreads();
#pragma unroll
  for (int p = 0; p < 4; ++p) {
    int nr = p * 16 + rr;
    short4 o;
    o.x = f2bs(Lt[cx * 4 + 0][nr]);
    o.y = f2bs(Lt[cx * 4 + 1][nr]);
    o.z = f2bs(Lt[cx * 4 + 2][nr]);
    o.w = f2bs(Lt[cx * 4 + 3][nr]);
    *reinterpret_cast<short4*>(out + (size_t)(n0 + nr) * CC + k0 + cx * 4) = o;
  }
}

// ---------------------------------------------------------------------------
// gemm128<QKV>: 128x128, BK=64, 4 waves, 2 blocks/CU.  R9 changes:
//
// (1) 2-phase/K-tile, SINGLE barrier per phase (was 4 phases x 2 barriers):
//     phase kc = { 8 ds_read frags(kc); stage 2 quanta; lgkmcnt(0);
//                  sched_barrier; 16 MFMA; counted vmcnt; s_barrier }.
//     Safety: frags read regions certified by the PREVIOUS phase's
//     vmcnt+barrier (block-wide); ds_read->MFMA is per-wave lgkmcnt(0)
//     (+sched_barrier, rule 18); each stage targets a region whose last
//     readers completed (their lgkmcnt) before the one barrier that
//     precedes this stage in program order -> WAR safe.
//     FIFO ledger (issue order kc0(0),kc1(0),kc0(1),kc1(1),... =
//     consumption order): steady vmcnt(8); tail ph1(u14)=vmcnt(4),
//     ph0(u15)=vmcnt(0).  Prologue: 6 quanta, vmcnt(8).
//
// (2) col-major-within-XCD block swizzle: each XCD owns 8 fixed A row
//     panels (2 MB, L2-resident for the whole kernel) and streams B one
//     256 KB panel at a time (R8 row-major order thrashed B: per-XCD set
//     was 2+6.3 MB > 4 MB L2 -> FETCH 133 MB; now ~67 MB).
// ---------------------------------------------------------------------------
template<bool QKV>
__global__ __launch_bounds__(256, 2)
void gemm128(const short* __restrict__ A, const short* __restrict__ Bt,
             const float* __restrict__ bias,
             short* __restrict__ qb, short* __restrict__ kb, short* __restrict__ vb,
             float* __restrict__ out)
{
  // A: [2 buf][2 kc][128][32] = 16384 shorts; B same at +16384. 64 KB total.
  __shared__ __align__(16) short SMEM[32768];

  const int t = threadIdx.x;
  const int lane = t & 63;
  const int l16 = lane & 15, quad = lane >> 4;
  const int w = t >> 6;
  const int wm = w & 1, wn = w >> 1;            // 2(M) x 2(N) wave grid

  // col-major-within-XCD swizzle: 64 row-strips = 8 XCD x 8; B cols stream.
  const int xcd   = blockIdx.x & 7;
  const int idx   = blockIdx.x >> 3;            // [0, 8*NBC)
  const int row0  = (xcd * 8 + (idx & 7)) * 128;
  const int col0  = (idx >> 3) * 128;

  auto stageQA = [&](int bufS, int kcS, int tileS) __attribute__((always_inline)) {
#pragma unroll
    for (int l = 0; l < 2; ++l) {
      int gq = l * 256 + t;                 // 16B-chunk id 0..511
      int rq = gq >> 2;                     // row 0..127
      int g  = (gq & 3) ^ ((rq >> 1) & 3);  // conflict-free involution
      gl_lds16(A + (size_t)(row0 + rq) * CC + tileS * 64 + kcS * 32 + g * 8,
               &SMEM[bufS * 8192 + kcS * 4096 + gq * 8]);
    }
  };
  auto stageQB = [&](int bufS, int kcS, int tileS) __attribute__((always_inline)) {
#pragma unroll
    for (int l = 0; l < 2; ++l) {
      int gq = l * 256 + t;
      int rq = gq >> 2;
      int g  = (gq & 3) ^ ((rq >> 1) & 3);
      gl_lds16(Bt + (size_t)(col0 + rq) * CC + tileS * 64 + kcS * 32 + g * 8,
               &SMEM[16384 + bufS * 8192 + kcS * 4096 + gq * 8]);
    }
  };

  f32x4 acc[4][4];
#pragma unroll
  for (int i = 0; i < 4; ++i)
#pragma unroll
    for (int j = 0; j < 4; ++j) acc[i][j] = (f32x4){0.f, 0.f, 0.f, 0.f};

  // tm: 0 = steady (u<=13), 1 = u14, 2 = u15
  auto kTile = [&](int u, int cb, int tm) __attribute__((always_inline)) {
    const short* Ac = &SMEM[cb * 8192];
    const short* Bc = &SMEM[16384 + cb * 8192];
#pragma unroll
    for (int kc = 0; kc < 2; ++kc) {
      short8 af[4], bf[4];
#pragma unroll
      for (int j = 0; j < 4; ++j) {
        int rb = wn * 64 + j * 16 + l16;
        bf[j] = *reinterpret_cast<const short8*>(
            &Bc[kc * 4096 + rb * 32 + (((quad ^ (rb >> 1)) & 3) << 3)]);
      }
#pragma unroll
      for (int i = 0; i < 4; ++i) {
        int ra = wm * 64 + i * 16 + l16;
        af[i] = *reinterpret_cast<const short8*>(
            &Ac[kc * 4096 + ra * 32 + (((quad ^ (ra >> 1)) & 3) << 3)]);
      }

      if (kc == 0) {               // stage kc1(u+1) into buf cb^1
        if (tm < 2) { stageQA(cb ^ 1, 1, u + 1); stageQB(cb ^ 1, 1, u + 1); }
      } else {                     // stage kc0(u+2) into buf cb
        if (tm < 1) { stageQA(cb,     0, u + 2); stageQB(cb,     0, u + 2); }
      }

      asm volatile("s_waitcnt lgkmcnt(0)" ::: "memory");
      __builtin_amdgcn_sched_barrier(0);

      __builtin_amdgcn_s_setprio(1);
#pragma unroll
      for (int i = 0; i < 4; ++i)
#pragma unroll
        for (int j = 0; j < 4; ++j)
          acc[i][j] = __builtin_amdgcn_mfma_f32_16x16x32_bf16(af[i], bf[j], acc[i][j], 0, 0, 0);
      __builtin_amdgcn_s_setprio(0);

      if (kc == 0) {
        if (tm == 2) { asm volatile("s_waitcnt vmcnt(0)" ::: "memory"); }
        else         { asm volatile("s_waitcnt vmcnt(8)" ::: "memory"); }
      } else {
        if      (tm == 0) { asm volatile("s_waitcnt vmcnt(8)" ::: "memory"); }
        else if (tm == 1) { asm volatile("s_waitcnt vmcnt(4)" ::: "memory"); }
      }
      __builtin_amdgcn_s_barrier();
    }
  };

  // prologue: 6 quanta in FIFO order kc0(0), kc1(0), kc0(1); certify kc0(0)
  stageQA(0, 0, 0);  stageQB(0, 0, 0);
  stageQA(0, 1, 0);  stageQB(0, 1, 0);
  stageQA(1, 0, 1);  stageQB(1, 0, 1);
  asm volatile("s_waitcnt vmcnt(8)" ::: "memory");
  __builtin_amdgcn_s_barrier();

  for (int u = 0; u < 14; u += 2) {
    kTile(u,     0, 0);
    kTile(u + 1, 1, 0);
  }
  kTile(14, 0, 1);
  kTile(15, 1, 2);

  if constexpr (QKV) {
    const int sel = col0 >> 10;                    // uniform per block
    const int bi  = row0 >> 11;
#pragma unroll
    for (int j = 0; j < 4; ++j) {
      const int colL = wn * 64 + j * 16 + l16;           // 0..127
      const float bv = bias[col0 + colL];
#pragma unroll
      for (int i = 0; i < 4; ++i)
#pragma unroll
        for (int r = 0; r < 4; ++r) {
          const int rl = wm * 64 + i * 16 + quad * 4 + r; // 0..127
          float val = acc[i][j][r] + bv;
          if (sel == 0) val *= QSCALE;
          short vs = f2bs(val);
          if (sel == 2) {
            int tpl = (rl & ~63) | ((rl & 15) << 2) | ((rl >> 4) & 3);
            SMEM[colL * 136 + tpl] = vs;
          } else {
            SMEM[rl * 136 + colL] = vs;
          }
        }
    }
    __syncthreads();
    if (sel == 0) {
      // q: flat [B,H,T,D] (128 B runs)
#pragma unroll
      for (int rep = 0; rep < 8; ++rep) {
        int slot = rep * 256 + t;
        int rl = slot >> 4, ch = slot & 15;
        short8 vv = *reinterpret_cast<const short8*>(&SMEM[rl * 136 + ch * 8]);
        int tt  = (row0 & 2047) + rl;
        int cin = (col0 + ch * 8) & 1023;
        int hh = cin >> 6, dd = cin & 63;
        *reinterpret_cast<short8*>(
            &qb[(((size_t)(bi * HH + hh)) * TT + tt) * DD + dd]) = vv;
      }
    } else if (sel == 1) {
      // k: 8KB tiles [hb][kt][row=t&63][slot], slot = g ^ ((rt>>1)&7)
#pragma unroll
      for (int rep = 0; rep < 8; ++rep) {
        int slot = rep * 256 + t;
        int rl = slot >> 4, ch = slot & 15;
        short8 vv = *reinterpret_cast<const short8*>(&SMEM[rl * 136 + ch * 8]);
        int tt  = (row0 & 2047) + rl;
        int cin = (col0 + ch * 8) & 1023;
        int hh = cin >> 6;
        int rt = tt & 63;
        int cs = ((cin >> 3) & 7) ^ ((rt >> 1) & 7);
        size_t tile = (size_t)(bi * HH + hh) * 32 + (tt >> 6);
        *reinterpret_cast<short8*>(&kb[tile * 4096 + rt * 64 + cs * 8]) = vv;
      }
    } else {
      // v: 8KB tiles [hb][kt][row=dd][slot over t-permuted cols]
#pragma unroll
      for (int rep = 0; rep < 8; ++rep) {
        int slot = rep * 256 + t;
        int dcol = slot >> 4, ch = slot & 15;
        short8 vv = *reinterpret_cast<const short8*>(&SMEM[dcol * 136 + ch * 8]);
        int cin = (col0 + dcol) & 1023;
        int hh = cin >> 6, dd = cin & 63;
        int ktv = ((row0 & 2047) >> 6) + (ch >> 3);
        int cs  = (ch & 7) ^ ((dd >> 1) & 7);
        *reinterpret_cast<short8*>(
            &vb[((size_t)(bi * HH + hh) * 32 + ktv) * 4096 + dd * 64 + cs * 8]) = vv;
      }
    }
  } else {
#pragma unroll
    for (int j = 0; j < 4; ++j) {
      int col = col0 + wn * 64 + j * 16 + l16;
      float bv = bias[col];
#pragma unroll
      for (int i = 0; i < 4; ++i)
#pragma unroll
        for (int r = 0; r < 4; ++r) {
          int row = row0 + wm * 64 + i * 16 + quad * 4 + r;
          out[(size_t)row * CC + col] = acc[i][j][r] + bv;
        }
    }
  }
}

// ---------------------------------------------------------------------------
// K2: MFMA flash attention, 32 q-rows per wave (R7/R8 body, unchanged).
// ---------------------------------------------------------------------------
__global__ __launch_bounds__(256, 2)
void attn_mfma(const short* __restrict__ Qb, const short* __restrict__ Kb,
               const short* __restrict__ Vb, short* __restrict__ Y)
{
  __shared__ __align__(16) short Kd[2][4096];
  __shared__ __align__(16) short Vt[4096];
  __shared__ __align__(16) short Pw[4 * 32 * LDST];

  const int t    = threadIdx.x;
  const int w    = t >> 6;
  const int lane = t & 63;
  const int l16  = lane & 15;
  const int quad = lane >> 4;

  // XCD-chunked bijective remap: 512 blocks -> XCD k owns nb in [64k,64k+64)
  const int linear = blockIdx.x + 8 * (blockIdx.y + 16 * blockIdx.z);
  const int nb  = (linear & 7) * 64 + (linear >> 3);
  const int qb0 = nb & 7;          // q-block pair id 0..7
  const int h   = (nb >> 3) & 15;
  const int bi  = nb >> 7;
  const size_t head = (size_t)(bi * HH + h) * TT * DD;   // == tile_base*4096

  short* myP = &Pw[w * 32 * LDST];

  auto stageK = [&](int kt, int p) __attribute__((always_inline)) {
    const short* src = Kb + head + (size_t)kt * 4096;
    gl_lds16(src + t * 8,        &Kd[p][t * 8]);
    gl_lds16(src + 2048 + t * 8, &Kd[p][2048 + t * 8]);
  };
  auto stageV = [&](int kt) __attribute__((always_inline)) {
    const short* src = Vb + head + (size_t)kt * 4096;
    gl_lds16(src + t * 8,        &Vt[t * 8]);
    gl_lds16(src + 2048 + t * 8, &Vt[2048 + t * 8]);
  };

  const int qbs[2] = { qb0, 15 - qb0 };

#pragma unroll
  for (int half = 0; half < 2; ++half) {
    const int qb  = qbs[half];
    const int q0  = qb * 128;
    const int nkt = 2 * qb + 2;     // k-tiles 0 .. 2qb+1 (>=2 always)

    short8 qf[2][2];
#pragma unroll
    for (int i = 0; i < 2; ++i)
#pragma unroll
      for (int kc = 0; kc < 2; ++kc)
        qf[i][kc] = *reinterpret_cast<const short8*>(
            &Qb[head + (size_t)(q0 + w * 32 + i * 16 + l16) * DD + kc * 32 + quad * 8]);

    f32x4 O[2][4];
#pragma unroll
    for (int i = 0; i < 2; ++i)
#pragma unroll
      for (int dt = 0; dt < 4; ++dt) O[i][dt] = (f32x4){0.f, 0.f, 0.f, 0.f};
    float lsum[2][4] = {};

    // prologue: K(0), V(0), K(1); certify qf + K(0)
    stageK(0, 0);
    stageV(0);
    stageK(1, 1);
    asm volatile("s_waitcnt vmcnt(4)" ::: "memory");
    __builtin_amdgcn_s_barrier();

    for (int kt = 0; kt < nkt; ++kt) {
      const int p  = kt & 1;
      const int k0 = kt * 64;

      short8 kf[4][2];
#pragma unroll
      for (int nt = 0; nt < 4; ++nt)
#pragma unroll
        for (int kc = 0; kc < 2; ++kc) {
          int r = nt * 16 + l16;
          int c = kc * 4 + quad;
          kf[nt][kc] = *reinterpret_cast<const short8*>(
              &Kd[p][r * 64 + ((c ^ ((r >> 1) & 7)) << 3)]);
        }

      f32x4 s[2][4];
#pragma unroll
      for (int i = 0; i < 2; ++i)
#pragma unroll
        for (int nt = 0; nt < 4; ++nt) s[i][nt] = (f32x4){0.f, 0.f, 0.f, 0.f};
      __builtin_amdgcn_s_setprio(1);
#pragma unroll
      for (int i = 0; i < 2; ++i)
#pragma unroll
        for (int nt = 0; nt < 4; ++nt)
#pragma unroll
          for (int kc = 0; kc < 2; ++kc)
            s[i][nt] = __builtin_amdgcn_mfma_f32_16x16x32_bf16(qf[i][kc], kf[nt][kc], s[i][nt], 0, 0, 0);
      __builtin_amdgcn_s_setprio(0);

#pragma unroll
      for (int i = 0; i < 2; ++i) {
        const int rowg_base = q0 + w * 32 + i * 16 + quad * 4;
#pragma unroll
        for (int r = 0; r < 4; ++r) {
          const int rowg = rowg_base + r;
          short pk[4];
#pragma unroll
          for (int nt = 0; nt < 4; ++nt) {
            float e = (k0 + nt * 16 + l16 <= rowg) ? __builtin_amdgcn_exp2f(s[i][nt][r]) : 0.f;
            lsum[i][r] += e;
            pk[nt] = f2bs(e);
          }
          short4 p4; p4.x = pk[0]; p4.y = pk[1]; p4.z = pk[2]; p4.w = pk[3];
          *reinterpret_cast<short4*>(&myP[(i * 16 + quad * 4 + r) * LDST + (l16 << 2)]) = p4;
        }
      }

      asm volatile("s_waitcnt vmcnt(0)" ::: "memory");  // V(kt), K(kt+1) landed
      __builtin_amdgcn_s_barrier();                     // barrier1 (block-wide)

      if (kt + 2 < nkt) stageK(kt + 2, p);              // Kd[p] free after barrier1

      __builtin_amdgcn_s_setprio(1);
#pragma unroll
      for (int cc = 0; cc < 2; ++cc) {
        short8 pf[2];
#pragma unroll
        for (int i = 0; i < 2; ++i)
          pf[i] = *reinterpret_cast<const short8*>(
              &myP[(i * 16 + l16) * LDST + cc * 32 + quad * 8]);
#pragma unroll
        for (int dt = 0; dt < 4; ++dt) {
          int r = dt * 16 + l16;
          int c = cc * 4 + quad;
          short8 vf = *reinterpret_cast<const short8*>(
              &Vt[r * 64 + ((c ^ ((r >> 1) & 7)) << 3)]);
#pragma unroll
          for (int i = 0; i < 2; ++i)
            O[i][dt] = __builtin_amdgcn_mfma_f32_16x16x32_bf16(pf[i], vf, O[i][dt], 0, 0, 0);
        }
      }
      __builtin_amdgcn_s_setprio(0);

      __builtin_amdgcn_s_barrier();                     // barrier2: Vt free
      if (kt + 1 < nkt) stageV(kt + 1);
    }

    float linv[2][4];
#pragma unroll
    for (int i = 0; i < 2; ++i)
#pragma unroll
      for (int r = 0; r < 4; ++r) {
        float s = lsum[i][r];
        s += __shfl_xor(s, 1);
        s += __shfl_xor(s, 2);
        s += __shfl_xor(s, 4);
        s += __shfl_xor(s, 8);
        linv[i][r] = 1.f / s;
      }
#pragma unroll
    for (int i = 0; i < 2; ++i)
#pragma unroll
      for (int dt = 0; dt < 4; ++dt)
#pragma unroll
        for (int r = 0; r < 4; ++r) {
          int tg = q0 + w * 32 + i * 16 + quad * 4 + r;
          Y[((size_t)bi * TT + tg) * CC + h * DD + dt * 16 + l16] =
              f2bs(O[i][dt][r] * linv[i][r]);
        }
  }
}

// ---------------------------------------------------------------------------
extern "C" void kernel_launch(void* const* d_in, const int* in_sizes, int n_in,
                              void* d_out, int out_size, void* d_ws, size_t ws_size,
                              hipStream_t stream) {
  const float* x  = (const float*)d_in[0];   // [4,2048,1024] fp32
  const float* Wa = (const float*)d_in[1];   // [1024,3072]  fp32
  const float* ba = (const float*)d_in[2];   // [3072]       fp32
  const float* Wp = (const float*)d_in[3];   // [1024,1024]  fp32
  const float* bp = (const float*)d_in[4];   // [1024]       fp32
  float* out = (float*)d_out;                // [4,2048,1024] fp32

  const size_t NELT = (size_t)BB * HH * TT * DD;   // 8388608
  short* qb  = (short*)d_ws;                       // bf16 [B,H,T,D] (pre-scaled)
  short* kb  = qb + NELT;                          // bf16 tiles [B*H][32][64][64] swz
  short* vb  = kb + NELT;                          // bf16 tiles [B*H][32][64][64] swz
  short* Xb  = vb + NELT;                          // [8192][1024] bf16
  short* Wat = Xb  + (size_t)BT * CC;              // [3072][1024] bf16 (Wa^T)
  short* Wpt = Wat + (size_t)CC * C3;              // [1024][1024] bf16 (Wp^T)
  short* Yb  = Wpt + (size_t)CC * CC;              // [8192][1024] bf16

  prep<<<dim3(64 + 256, 16), 256, 0, stream>>>(Wa, Wat, Wp, Wpt, x, Xb);

  gemm128<true> <<<dim3((BT / 128) * (C3 / 128)), 256, 0, stream>>>(Xb, Wat, ba, qb, kb, vb, nullptr);
  attn_mfma     <<<dim3(8, HH, BB),               256, 0, stream>>>(qb, kb, vb, Yb);
  gemm128<false><<<dim3((BT / 128) * (CC / 128)), 256, 0, stream>>>(Yb, Wpt, bp, nullptr, nullptr, nullptr, out);
}

// Round 10
// 229.275 us; speedup vs baseline: 1.1086x; 1.0159x over previous
//
#include <hip/hip_runtime.h>
#include <hip/hip_bf16.h>

#define BB 4
#define TT 2048
#define CC 1024
#define HH 16
#define DD 64
#define BT (BB*TT)   // 8192
#define C3 (3*CC)    // 3072
#define LDST 72      // attn P-buffer row stride in bf16 elems (144 B)
#define QSCALE 0.18033688011112042f   // 0.125 * log2(e)

typedef __attribute__((ext_vector_type(8))) short short8;
typedef __attribute__((ext_vector_type(4))) float f32x4;

__device__ __forceinline__ short f2bs(float f) {
  __hip_bfloat16 h = __float2bfloat16(f);
  return *reinterpret_cast<short*>(&h);
}

__device__ __forceinline__ void gl_lds16(const short* g, short* l) {
  __builtin_amdgcn_global_load_lds(
      (const __attribute__((address_space(1))) void*)(g),
      (__attribute__((address_space(3))) void*)(l), 16, 0, 0);
}

// ---------------------------------------------------------------------------
// P: single prep launch (verified, unchanged).
// ---------------------------------------------------------------------------
__global__ __launch_bounds__(256)
void prep(const float* __restrict__ Wa, short* __restrict__ Wat,
          const float* __restrict__ Wp, short* __restrict__ Wpt,
          const float* __restrict__ x, short* __restrict__ Xb)
{
  __shared__ float Lt[64][65];
  const int bx = blockIdx.x;
  if (bx >= 64) {
    size_t chunk = (size_t)(bx - 64) * 16 + blockIdx.y;
    size_t i = (chunk * 256 + threadIdx.x) * 8;
    float4 a = *reinterpret_cast<const float4*>(x + i);
    float4 b = *reinterpret_cast<const float4*>(x + i + 4);
    short8 o;
    o[0] = f2bs(a.x); o[1] = f2bs(a.y); o[2] = f2bs(a.z); o[3] = f2bs(a.w);
    o[4] = f2bs(b.x); o[5] = f2bs(b.y); o[6] = f2bs(b.z); o[7] = f2bs(b.w);
    *reinterpret_cast<short8*>(Xb + i) = o;
    return;
  }
  const bool isA = (bx < 48);
  const float* in  = isA ? Wa  : Wp;
  short*       out = isA ? Wat : Wpt;
  const int N  = isA ? C3 : CC;
  const int n0 = (isA ? bx : bx - 48) * 64;
  const int k0 = blockIdx.y * 64;
  const int cx = threadIdx.x & 15, rr = threadIdx.x >> 4;
#pragma unroll
  for (int p = 0; p < 4; ++p) {
    int kr = p * 16 + rr;
    float4 u = *reinterpret_cast<const float4*>(in + (size_t)(k0 + kr) * N + n0 + cx * 4);
    Lt[kr][cx * 4 + 0] = u.x;
    Lt[kr][cx * 4 + 1] = u.y;
    Lt[kr][cx * 4 + 2] = u.z;
    Lt[kr][cx * 4 + 3] = u.w;
  }
  __syncthreads();
#pragma unroll
  for (int p = 0; p < 4; ++p) {
    int nr = p * 16 + rr;
    short4 o;
    o.x = f2bs(Lt[cx * 4 + 0][nr]);
    o.y = f2bs(Lt[cx * 4 + 1][nr]);
    o.z = f2bs(Lt[cx * 4 + 2][nr]);
    o.w = f2bs(Lt[cx * 4 + 3][nr]);
    *reinterpret_cast<short4*>(out + (size_t)(n0 + nr) * CC + k0 + cx * 4) = o;
  }
}

// ---------------------------------------------------------------------------
// gemm128<QKV>: 128x128, BK=64, 4 waves, 2 blocks/CU. R9-verified:
// 2-phase/K-tile single-barrier counted-vmcnt ledger + col-major-within-XCD
// swizzle (A panels L2-resident, FETCH 46 MB). UNCHANGED this round.
// ---------------------------------------------------------------------------
template<bool QKV>
__global__ __launch_bounds__(256, 2)
void gemm128(const short* __restrict__ A, const short* __restrict__ Bt,
             const float* __restrict__ bias,
             short* __restrict__ qb, short* __restrict__ kb, short* __restrict__ vb,
             float* __restrict__ out)
{
  // A: [2 buf][2 kc][128][32] = 16384 shorts; B same at +16384. 64 KB total.
  __shared__ __align__(16) short SMEM[32768];

  const int t = threadIdx.x;
  const int lane = t & 63;
  const int l16 = lane & 15, quad = lane >> 4;
  const int w = t >> 6;
  const int wm = w & 1, wn = w >> 1;            // 2(M) x 2(N) wave grid

  // col-major-within-XCD swizzle: 64 row-strips = 8 XCD x 8; B cols stream.
  const int xcd   = blockIdx.x & 7;
  const int idx   = blockIdx.x >> 3;            // [0, 8*NBC)
  const int row0  = (xcd * 8 + (idx & 7)) * 128;
  const int col0  = (idx >> 3) * 128;

  auto stageQA = [&](int bufS, int kcS, int tileS) __attribute__((always_inline)) {
#pragma unroll
    for (int l = 0; l < 2; ++l) {
      int gq = l * 256 + t;                 // 16B-chunk id 0..511
      int rq = gq >> 2;                     // row 0..127
      int g  = (gq & 3) ^ ((rq >> 1) & 3);  // conflict-free involution
      gl_lds16(A + (size_t)(row0 + rq) * CC + tileS * 64 + kcS * 32 + g * 8,
               &SMEM[bufS * 8192 + kcS * 4096 + gq * 8]);
    }
  };
  auto stageQB = [&](int bufS, int kcS, int tileS) __attribute__((always_inline)) {
#pragma unroll
    for (int l = 0; l < 2; ++l) {
      int gq = l * 256 + t;
      int rq = gq >> 2;
      int g  = (gq & 3) ^ ((rq >> 1) & 3);
      gl_lds16(Bt + (size_t)(col0 + rq) * CC + tileS * 64 + kcS * 32 + g * 8,
               &SMEM[16384 + bufS * 8192 + kcS * 4096 + gq * 8]);
    }
  };

  f32x4 acc[4][4];
#pragma unroll
  for (int i = 0; i < 4; ++i)
#pragma unroll
    for (int j = 0; j < 4; ++j) acc[i][j] = (f32x4){0.f, 0.f, 0.f, 0.f};

  // tm: 0 = steady (u<=13), 1 = u14, 2 = u15
  auto kTile = [&](int u, int cb, int tm) __attribute__((always_inline)) {
    const short* Ac = &SMEM[cb * 8192];
    const short* Bc = &SMEM[16384 + cb * 8192];
#pragma unroll
    for (int kc = 0; kc < 2; ++kc) {
      short8 af[4], bf[4];
#pragma unroll
      for (int j = 0; j < 4; ++j) {
        int rb = wn * 64 + j * 16 + l16;
        bf[j] = *reinterpret_cast<const short8*>(
            &Bc[kc * 4096 + rb * 32 + (((quad ^ (rb >> 1)) & 3) << 3)]);
      }
#pragma unroll
      for (int i = 0; i < 4; ++i) {
        int ra = wm * 64 + i * 16 + l16;
        af[i] = *reinterpret_cast<const short8*>(
            &Ac[kc * 4096 + ra * 32 + (((quad ^ (ra >> 1)) & 3) << 3)]);
      }

      if (kc == 0) {               // stage kc1(u+1) into buf cb^1
        if (tm < 2) { stageQA(cb ^ 1, 1, u + 1); stageQB(cb ^ 1, 1, u + 1); }
      } else {                     // stage kc0(u+2) into buf cb
        if (tm < 1) { stageQA(cb,     0, u + 2); stageQB(cb,     0, u + 2); }
      }

      asm volatile("s_waitcnt lgkmcnt(0)" ::: "memory");
      __builtin_amdgcn_sched_barrier(0);

      __builtin_amdgcn_s_setprio(1);
#pragma unroll
      for (int i = 0; i < 4; ++i)
#pragma unroll
        for (int j = 0; j < 4; ++j)
          acc[i][j] = __builtin_amdgcn_mfma_f32_16x16x32_bf16(af[i], bf[j], acc[i][j], 0, 0, 0);
      __builtin_amdgcn_s_setprio(0);

      if (kc == 0) {
        if (tm == 2) { asm volatile("s_waitcnt vmcnt(0)" ::: "memory"); }
        else         { asm volatile("s_waitcnt vmcnt(8)" ::: "memory"); }
      } else {
        if      (tm == 0) { asm volatile("s_waitcnt vmcnt(8)" ::: "memory"); }
        else if (tm == 1) { asm volatile("s_waitcnt vmcnt(4)" ::: "memory"); }
      }
      __builtin_amdgcn_s_barrier();
    }
  };

  // prologue: 6 quanta in FIFO order kc0(0), kc1(0), kc0(1); certify kc0(0)
  stageQA(0, 0, 0);  stageQB(0, 0, 0);
  stageQA(0, 1, 0);  stageQB(0, 1, 0);
  stageQA(1, 0, 1);  stageQB(1, 0, 1);
  asm volatile("s_waitcnt vmcnt(8)" ::: "memory");
  __builtin_amdgcn_s_barrier();

  for (int u = 0; u < 14; u += 2) {
    kTile(u,     0, 0);
    kTile(u + 1, 1, 0);
  }
  kTile(14, 0, 1);
  kTile(15, 1, 2);

  if constexpr (QKV) {
    const int sel = col0 >> 10;                    // uniform per block
    const int bi  = row0 >> 11;
#pragma unroll
    for (int j = 0; j < 4; ++j) {
      const int colL = wn * 64 + j * 16 + l16;           // 0..127
      const float bv = bias[col0 + colL];
#pragma unroll
      for (int i = 0; i < 4; ++i)
#pragma unroll
        for (int r = 0; r < 4; ++r) {
          const int rl = wm * 64 + i * 16 + quad * 4 + r; // 0..127
          float val = acc[i][j][r] + bv;
          if (sel == 0) val *= QSCALE;
          short vs = f2bs(val);
          if (sel == 2) {
            int tpl = (rl & ~63) | ((rl & 15) << 2) | ((rl >> 4) & 3);
            SMEM[colL * 136 + tpl] = vs;
          } else {
            SMEM[rl * 136 + colL] = vs;
          }
        }
    }
    __syncthreads();
    if (sel == 0) {
      // q: flat [B,H,T,D] (128 B runs)
#pragma unroll
      for (int rep = 0; rep < 8; ++rep) {
        int slot = rep * 256 + t;
        int rl = slot >> 4, ch = slot & 15;
        short8 vv = *reinterpret_cast<const short8*>(&SMEM[rl * 136 + ch * 8]);
        int tt  = (row0 & 2047) + rl;
        int cin = (col0 + ch * 8) & 1023;
        int hh = cin >> 6, dd = cin & 63;
        *reinterpret_cast<short8*>(
            &qb[(((size_t)(bi * HH + hh)) * TT + tt) * DD + dd]) = vv;
      }
    } else if (sel == 1) {
      // k: 8KB tiles [hb][kt][row=t&63][slot], slot = g ^ ((rt>>1)&7)
#pragma unroll
      for (int rep = 0; rep < 8; ++rep) {
        int slot = rep * 256 + t;
        int rl = slot >> 4, ch = slot & 15;
        short8 vv = *reinterpret_cast<const short8*>(&SMEM[rl * 136 + ch * 8]);
        int tt  = (row0 & 2047) + rl;
        int cin = (col0 + ch * 8) & 1023;
        int hh = cin >> 6;
        int rt = tt & 63;
        int cs = ((cin >> 3) & 7) ^ ((rt >> 1) & 7);
        size_t tile = (size_t)(bi * HH + hh) * 32 + (tt >> 6);
        *reinterpret_cast<short8*>(&kb[tile * 4096 + rt * 64 + cs * 8]) = vv;
      }
    } else {
      // v: 8KB tiles [hb][kt][row=dd][slot over t-permuted cols]
#pragma unroll
      for (int rep = 0; rep < 8; ++rep) {
        int slot = rep * 256 + t;
        int dcol = slot >> 4, ch = slot & 15;
        short8 vv = *reinterpret_cast<const short8*>(&SMEM[dcol * 136 + ch * 8]);
        int cin = (col0 + dcol) & 1023;
        int hh = cin >> 6, dd = cin & 63;
        int ktv = ((row0 & 2047) >> 6) + (ch >> 3);
        int cs  = (ch & 7) ^ ((dd >> 1) & 7);
        *reinterpret_cast<short8*>(
            &vb[((size_t)(bi * HH + hh) * 32 + ktv) * 4096 + dd * 64 + cs * 8]) = vv;
      }
    }
  } else {
#pragma unroll
    for (int j = 0; j < 4; ++j) {
      int col = col0 + wn * 64 + j * 16 + l16;
      float bv = bias[col];
#pragma unroll
      for (int i = 0; i < 4; ++i)
#pragma unroll
        for (int r = 0; r < 4; ++r) {
          int row = row0 + wm * 64 + i * 16 + quad * 4 + r;
          out[(size_t)row * CC + col] = acc[i][j][r] + bv;
        }
    }
  }
}

// ---------------------------------------------------------------------------
// K2: MFMA flash attention, 32 q-rows/wave. R10 changes (sync restructure):
//   (a) V double-buffered (Vt[2]): stage V(u+1) right after barrier1 into
//       Vt[(u+1)&1] — that slot's readers (PV of u-1) all passed barrier1(u).
//   (b) barrier2 DELETED (its only purpose was the Vt WAR, now gone).
//       Per-iter sync = one vmcnt(0) + one barrier.  Kd restage stays safe:
//       every wave's QK reads of Kd[u&1] precede barrier1(u) in program
//       order; PV(u) precedes QK(u+1) precedes barrier1(u+1).
//   (c) 3 blocks/CU: LDS 16+16+18 = 50 KB, __launch_bounds__(256,3)
//       (VGPR cap 170; est. peak ~145) — 12 waves/CU to fill the serial
//       QK -> softmax -> PV chain.
// Ledger: prologue K(0),V(0),K(1) (6 loads), vmcnt(4) certifies K(0).
//   iter u: QK(Kd[u&1]); softmax->Pw; vmcnt(0) [drains V(u),K(u+1)];
//   barrier; stageK(u+2)->Kd[u&1]; stageV(u+1)->Vt[(u+1)&1]; PV(Vt[u&1]).
// ---------------------------------------------------------------------------
__global__ __launch_bounds__(256, 3)
void attn_mfma(const short* __restrict__ Qb, const short* __restrict__ Kb,
               const short* __restrict__ Vb, short* __restrict__ Y)
{
  __shared__ __align__(16) short Kd[2][4096];
  __shared__ __align__(16) short Vt[2][4096];
  __shared__ __align__(16) short Pw[4 * 32 * LDST];

  const int t    = threadIdx.x;
  const int w    = t >> 6;
  const int lane = t & 63;
  const int l16  = lane & 15;
  const int quad = lane >> 4;

  // XCD-chunked bijective remap: 512 blocks -> XCD k owns nb in [64k,64k+64)
  const int linear = blockIdx.x + 8 * (blockIdx.y + 16 * blockIdx.z);
  const int nb  = (linear & 7) * 64 + (linear >> 3);
  const int qb0 = nb & 7;          // q-block pair id 0..7
  const int h   = (nb >> 3) & 15;
  const int bi  = nb >> 7;
  const size_t head = (size_t)(bi * HH + h) * TT * DD;   // == tile_base*4096

  short* myP = &Pw[w * 32 * LDST];

  auto stageK = [&](int kt, int p) __attribute__((always_inline)) {
    const short* src = Kb + head + (size_t)kt * 4096;
    gl_lds16(src + t * 8,        &Kd[p][t * 8]);
    gl_lds16(src + 2048 + t * 8, &Kd[p][2048 + t * 8]);
  };
  auto stageV = [&](int kt, int p) __attribute__((always_inline)) {
    const short* src = Vb + head + (size_t)kt * 4096;
    gl_lds16(src + t * 8,        &Vt[p][t * 8]);
    gl_lds16(src + 2048 + t * 8, &Vt[p][2048 + t * 8]);
  };

  const int qbs[2] = { qb0, 15 - qb0 };

#pragma unroll
  for (int half = 0; half < 2; ++half) {
    const int qb  = qbs[half];
    const int q0  = qb * 128;
    const int nkt = 2 * qb + 2;     // k-tiles 0 .. 2qb+1 (>=2 always)

    short8 qf[2][2];
#pragma unroll
    for (int i = 0; i < 2; ++i)
#pragma unroll
      for (int kc = 0; kc < 2; ++kc)
        qf[i][kc] = *reinterpret_cast<const short8*>(
            &Qb[head + (size_t)(q0 + w * 32 + i * 16 + l16) * DD + kc * 32 + quad * 8]);

    f32x4 O[2][4];
#pragma unroll
    for (int i = 0; i < 2; ++i)
#pragma unroll
      for (int dt = 0; dt < 4; ++dt) O[i][dt] = (f32x4){0.f, 0.f, 0.f, 0.f};
    float lsum[2][4] = {};

    // prologue: K(0), V(0), K(1); certify qf + K(0) (keep V(0),K(1) flying)
    stageK(0, 0);
    stageV(0, 0);
    stageK(1, 1);
    asm volatile("s_waitcnt vmcnt(4)" ::: "memory");
    __builtin_amdgcn_s_barrier();

    for (int kt = 0; kt < nkt; ++kt) {
      const int p  = kt & 1;
      const int k0 = kt * 64;

      short8 kf[4][2];
#pragma unroll
      for (int nt = 0; nt < 4; ++nt)
#pragma unroll
        for (int kc = 0; kc < 2; ++kc) {
          int r = nt * 16 + l16;
          int c = kc * 4 + quad;
          kf[nt][kc] = *reinterpret_cast<const short8*>(
              &Kd[p][r * 64 + ((c ^ ((r >> 1) & 7)) << 3)]);
        }

      f32x4 s[2][4];
#pragma unroll
      for (int i = 0; i < 2; ++i)
#pragma unroll
        for (int nt = 0; nt < 4; ++nt) s[i][nt] = (f32x4){0.f, 0.f, 0.f, 0.f};
      __builtin_amdgcn_s_setprio(1);
#pragma unroll
      for (int i = 0; i < 2; ++i)
#pragma unroll
        for (int nt = 0; nt < 4; ++nt)
#pragma unroll
          for (int kc = 0; kc < 2; ++kc)
            s[i][nt] = __builtin_amdgcn_mfma_f32_16x16x32_bf16(qf[i][kc], kf[nt][kc], s[i][nt], 0, 0, 0);
      __builtin_amdgcn_s_setprio(0);

#pragma unroll
      for (int i = 0; i < 2; ++i) {
        const int rowg_base = q0 + w * 32 + i * 16 + quad * 4;
#pragma unroll
        for (int r = 0; r < 4; ++r) {
          const int rowg = rowg_base + r;
          short pk[4];
#pragma unroll
          for (int nt = 0; nt < 4; ++nt) {
            float e = (k0 + nt * 16 + l16 <= rowg) ? __builtin_amdgcn_exp2f(s[i][nt][r]) : 0.f;
            lsum[i][r] += e;
            pk[nt] = f2bs(e);
          }
          short4 p4; p4.x = pk[0]; p4.y = pk[1]; p4.z = pk[2]; p4.w = pk[3];
          *reinterpret_cast<short4*>(&myP[(i * 16 + quad * 4 + r) * LDST + (l16 << 2)]) = p4;
        }
      }

      asm volatile("s_waitcnt vmcnt(0)" ::: "memory");  // V(kt), K(kt+1) landed
      __builtin_amdgcn_s_barrier();                     // the ONE barrier

      if (kt + 2 < nkt) stageK(kt + 2, p);              // Kd[p]: QK reads done pre-barrier
      if (kt + 1 < nkt) stageV(kt + 1, p ^ 1);          // Vt[p^1]: PV(kt-1) readers done

      __builtin_amdgcn_s_setprio(1);
#pragma unroll
      for (int cc = 0; cc < 2; ++cc) {
        short8 pf[2];
#pragma unroll
        for (int i = 0; i < 2; ++i)
          pf[i] = *reinterpret_cast<const short8*>(
              &myP[(i * 16 + l16) * LDST + cc * 32 + quad * 8]);
#pragma unroll
        for (int dt = 0; dt < 4; ++dt) {
          int r = dt * 16 + l16;
          int c = cc * 4 + quad;
          short8 vf = *reinterpret_cast<const short8*>(
              &Vt[p][r * 64 + ((c ^ ((r >> 1) & 7)) << 3)]);
#pragma unroll
          for (int i = 0; i < 2; ++i)
            O[i][dt] = __builtin_amdgcn_mfma_f32_16x16x32_bf16(pf[i], vf, O[i][dt], 0, 0, 0);
        }
      }
      __builtin_amdgcn_s_setprio(0);
    }

    float linv[2][4];
#pragma unroll
    for (int i = 0; i < 2; ++i)
#pragma unroll
      for (int r = 0; r < 4; ++r) {
        float s = lsum[i][r];
        s += __shfl_xor(s, 1);
        s += __shfl_xor(s, 2);
        s += __shfl_xor(s, 4);
        s += __shfl_xor(s, 8);
        linv[i][r] = 1.f / s;
      }
#pragma unroll
    for (int i = 0; i < 2; ++i)
#pragma unroll
      for (int dt = 0; dt < 4; ++dt)
#pragma unroll
        for (int r = 0; r < 4; ++r) {
          int tg = q0 + w * 32 + i * 16 + quad * 4 + r;
          Y[((size_t)bi * TT + tg) * CC + h * DD + dt * 16 + l16] =
              f2bs(O[i][dt][r] * linv[i][r]);
        }
  }
}

// ---------------------------------------------------------------------------
extern "C" void kernel_launch(void* const* d_in, const int* in_sizes, int n_in,
                              void* d_out, int out_size, void* d_ws, size_t ws_size,
                              hipStream_t stream) {
  const float* x  = (const float*)d_in[0];   // [4,2048,1024] fp32
  const float* Wa = (const float*)d_in[1];   // [1024,3072]  fp32
  const float* ba = (const float*)d_in[2];   // [3072]       fp32
  const float* Wp = (const float*)d_in[3];   // [1024,1024]  fp32
  const float* bp = (const float*)d_in[4];   // [1024]       fp32
  float* out = (float*)d_out;                // [4,2048,1024] fp32

  const size_t NELT = (size_t)BB * HH * TT * DD;   // 8388608
  short* qb  = (short*)d_ws;                       // bf16 [B,H,T,D] (pre-scaled)
  short* kb  = qb + NELT;                          // bf16 tiles [B*H][32][64][64] swz
  short* vb  = kb + NELT;                          // bf16 tiles [B*H][32][64][64] swz
  short* Xb  = vb + NELT;                          // [8192][1024] bf16
  short* Wat = Xb  + (size_t)BT * CC;              // [3072][1024] bf16 (Wa^T)
  short* Wpt = Wat + (size_t)CC * C3;              // [1024][1024] bf16 (Wp^T)
  short* Yb  = Wpt + (size_t)CC * CC;              // [8192][1024] bf16

  prep<<<dim3(64 + 256, 16), 256, 0, stream>>>(Wa, Wat, Wp, Wpt, x, Xb);

  gemm128<true> <<<dim3((BT / 128) * (C3 / 128)), 256, 0, stream>>>(Xb, Wat, ba, qb, kb, vb, nullptr);
  attn_mfma     <<<dim3(8, HH, BB),               256, 0, stream>>>(qb, kb, vb, Yb);
  gemm128<false><<<dim3((BT / 128) * (CC / 128)), 256, 0, stream>>>(Yb, Wpt, bp, nullptr, nullptr, nullptr, out);
}